// Round 3
// baseline (1231.770 us; speedup 1.0000x reference)
//
#include <hip/hip_runtime.h>
#include <hip/hip_bf16.h>

typedef __hip_bfloat16 bf16;

#define N_NODES 100000
#define N_EDGES 1600000
#define D 128

// ---- dtype probe: are the float tensors bf16 (flag=1) or fp32 (flag=0)? ----
// For true bf16 data, the low 16 bits of each 32b word are a bf16 N(0,1) value
// (exponent 107..147 essentially always). For fp32 data they are random
// mantissa bits (exponent field ~uniform -> ~16% in range). Threshold 75%.
__global__ void probe_kernel(const unsigned int* __restrict__ xw, int* __restrict__ flag) {
    __shared__ int cnt;
    if (threadIdx.x == 0) cnt = 0;
    __syncthreads();
    unsigned int w = xw[threadIdx.x];
    unsigned int low = w & 0xFFFFu;
    unsigned int e = (low >> 7) & 0xFFu;
    int ok = (e == 0u) || (e >= 107u && e <= 147u);
    atomicAdd(&cnt, ok);
    __syncthreads();
    if (threadIdx.x == 0) *flag = (cnt >= 192) ? 1 : 0;
}

// canonicalize W -> bf16 in ws, b -> fp32 in ws (branch on flag)
__global__ void convert_kernel(const void* __restrict__ W, const void* __restrict__ b,
                               const int* __restrict__ flag,
                               bf16* __restrict__ Wb, float* __restrict__ bf) {
    int i = blockIdx.x * 256 + threadIdx.x;
    int m = *flag;
    if (i < D * D)
        Wb[i] = m ? ((const bf16*)W)[i] : __float2bfloat16(((const float*)W)[i]);
    if (i < D)
        bf[i] = m ? __bfloat162float(((const bf16*)b)[i]) : ((const float*)b)[i];
}

__global__ void deg_init_kernel(float* __restrict__ deg) {
    int i = blockIdx.x * 256 + threadIdx.x;
    if (i < N_NODES) deg[i] = 1.0f;  // self-loop
}

__global__ void deg_count_kernel(const int* __restrict__ dst, float* __restrict__ deg) {
    int e = blockIdx.x * 256 + threadIdx.x;
    if (e < N_EDGES) atomicAdd(&deg[dst[e]], 1.0f);
}

__global__ void dis_kernel(const float* __restrict__ deg, float* __restrict__ dis) {
    int i = blockIdx.x * 256 + threadIdx.x;
    if (i < N_NODES) dis[i] = rsqrtf(deg[i]);
}

// h = x @ W  (N x 128)@(128 x 128), h -> bf16 in ws.
// 256 threads / block handle 64 rows; W staged in LDS (32 KB bf16).
__global__ void gemm_kernel(const void* __restrict__ xv, const bf16* __restrict__ Wb,
                            const int* __restrict__ flag, bf16* __restrict__ h) {
    __shared__ bf16 Wl[D * D];
    __shared__ bf16 xs[2 * D];
    int tid = threadIdx.x;
    int m = *flag;
    for (int idx = tid; idx < D * D; idx += 256) Wl[idx] = Wb[idx];
    __syncthreads();

    int row0 = blockIdx.x * 64;
    int rl = tid >> 7;
    int j  = tid & 127;

    for (int rr = 0; rr < 64; rr += 2) {
        int r = row0 + rr + rl;
        if (r < N_NODES) {
            size_t off = (size_t)r * D + j;
            xs[tid] = m ? ((const bf16*)xv)[off]
                        : __float2bfloat16(((const float*)xv)[off]);
        }
        __syncthreads();
        if (r < N_NODES) {
            float sum = 0.0f;
            const bf16* xr = &xs[rl * D];
            #pragma unroll
            for (int k = 0; k < D; ++k)
                sum += __bfloat162float(xr[k]) * __bfloat162float(Wl[k * D + j]);
            h[(size_t)r * D + j] = __float2bfloat16(sum);
        }
        __syncthreads();
    }
}

// per edge: acc[dst][:] += h[src][:] * dis[src]*dis[dst]  (128 lanes per edge)
__global__ void scatter_kernel(const int* __restrict__ src, const int* __restrict__ dst,
                               const float* __restrict__ dis, const bf16* __restrict__ h,
                               float* __restrict__ acc) {
    long long t = (long long)blockIdx.x * 256 + threadIdx.x;
    int e = (int)(t >> 7);
    int j = (int)(t & 127);
    if (e < N_EDGES) {
        int s = src[e];
        int d = dst[e];
        float w = dis[s] * dis[d];
        float msg = __bfloat162float(h[(size_t)s * D + j]) * w;
        atomicAdd(&acc[(size_t)d * D + j], msg);
    }
}

// out = relu(acc + h * (1/deg) + b), store per flag dtype
__global__ void finalize_kernel(const float* __restrict__ acc, const bf16* __restrict__ h,
                                const float* __restrict__ dis, const float* __restrict__ bf,
                                const int* __restrict__ flag, void* __restrict__ out) {
    long long t = (long long)blockIdx.x * 256 + threadIdx.x;
    if (t < (long long)N_NODES * D) {
        int n = (int)(t >> 7);
        int j = (int)(t & 127);
        float di = dis[n];
        float v = acc[t] + __bfloat162float(h[t]) * di * di + bf[j];
        v = v > 0.0f ? v : 0.0f;
        if (*flag) ((bf16*)out)[t] = __float2bfloat16(v);
        else       ((float*)out)[t] = v;
    }
}

extern "C" void kernel_launch(void* const* d_in, const int* in_sizes, int n_in,
                              void* d_out, int out_size, void* d_ws, size_t ws_size,
                              hipStream_t stream) {
    // Bind inputs by flat size; fall back to dict order if sizes don't match.
    const void* x = nullptr; const int* ei = nullptr;
    const void* W = nullptr; const void* b = nullptr;
    for (int i = 0; i < n_in; ++i) {
        if      (in_sizes[i] == N_NODES * D)  x  = d_in[i];
        else if (in_sizes[i] == 2 * N_EDGES)  ei = (const int*)d_in[i];
        else if (in_sizes[i] == D * D)        W  = d_in[i];
        else if (in_sizes[i] == D)            b  = d_in[i];
    }
    if (!x || !ei || !W || !b) {
        x  = d_in[0];
        ei = (const int*)d_in[1];
        W  = d_in[2];
        b  = d_in[3];
    }

    const int* src = ei;            // edge_index[0]
    const int* dst = ei + N_EDGES;  // edge_index[1]

    // ws layout: flag(16B) | deg N f32 | dis N f32 | b 128 f32 | W 16384 bf16 |
    //            h N*D bf16 | acc N*D f32   (~77.6 MB total)
    char* ws = (char*)d_ws;
    int*   flag = (int*)ws;
    float* deg  = (float*)(ws + 16);
    float* dis  = deg + N_NODES;
    float* bf   = dis + N_NODES;
    bf16*  Wb   = (bf16*)(bf + D);
    bf16*  h    = Wb + D * D;
    float* acc  = (float*)(h + (size_t)N_NODES * D);

    hipMemsetAsync(acc, 0, sizeof(float) * (size_t)N_NODES * D, stream);

    probe_kernel<<<1, 256, 0, stream>>>((const unsigned int*)x, flag);
    convert_kernel<<<(D * D + 255) / 256, 256, 0, stream>>>(W, b, flag, Wb, bf);

    deg_init_kernel<<<(N_NODES + 255) / 256, 256, 0, stream>>>(deg);
    deg_count_kernel<<<(N_EDGES + 255) / 256, 256, 0, stream>>>(dst, deg);
    dis_kernel<<<(N_NODES + 255) / 256, 256, 0, stream>>>(deg, dis);

    gemm_kernel<<<(N_NODES + 63) / 64, 256, 0, stream>>>(x, Wb, flag, h);

    long long scatter_threads = (long long)N_EDGES * D;
    scatter_kernel<<<(int)((scatter_threads + 255) / 256), 256, 0, stream>>>(src, dst, dis, h, acc);

    long long fin_threads = (long long)N_NODES * D;
    finalize_kernel<<<(int)((fin_threads + 255) / 256), 256, 0, stream>>>(acc, h, dis, bf, flag, d_out);
}

// Round 4
// 478.202 us; speedup vs baseline: 2.5758x; 2.5758x over previous
//
#include <hip/hip_runtime.h>

#define N_NODES 100000
#define N_EDGES 1600000
#define D 128

typedef __attribute__((ext_vector_type(8))) short short8;
typedef __attribute__((ext_vector_type(4))) float float4v;

__device__ inline unsigned short f2bf(float f) {
    unsigned u = __float_as_uint(f);
    unsigned r = (u + 0x7fffu + ((u >> 16) & 1u)) >> 16;   // RNE
    return (unsigned short)r;
}
__device__ inline float bflo(unsigned int p) { return __uint_as_float(p << 16); }
__device__ inline float bfhi(unsigned int p) { return __uint_as_float(p & 0xffff0000u); }

__global__ void probe_kernel(const unsigned int* __restrict__ xw, int* __restrict__ flag) {
    __shared__ int cnt;
    if (threadIdx.x == 0) cnt = 0;
    __syncthreads();
    unsigned int low = xw[threadIdx.x] & 0xFFFFu;
    unsigned int e = (low >> 7) & 0xFFu;
    atomicAdd(&cnt, (e == 0u) || (e >= 107u && e <= 147u));
    __syncthreads();
    if (threadIdx.x == 0) *flag = (cnt >= 192) ? 1 : 0;
}

__global__ void convert_b_kernel(const void* __restrict__ b, const int* __restrict__ flag,
                                 float* __restrict__ bfv) {
    int i = threadIdx.x;
    if (i < D)
        bfv[i] = *flag ? bflo(((const unsigned short*)b)[i]) : ((const float*)b)[i];
}

__global__ void deg_count_kernel(const int* __restrict__ dst, int* __restrict__ deg) {
    int e = blockIdx.x * 256 + threadIdx.x;
    if (e < N_EDGES) atomicAdd(&deg[dst[e]], 1);
}

__global__ void dis_kernel(const int* __restrict__ deg, float* __restrict__ dis) {
    int i = blockIdx.x * 256 + threadIdx.x;
    if (i < N_NODES) dis[i] = rsqrtf((float)(deg[i] + 1));  // +1 self-loop
}

__global__ void rowstart_kernel(const int* __restrict__ deg, int* __restrict__ cursor,
                                int* __restrict__ row_start, int* __restrict__ cur) {
    int i = blockIdx.x * 256 + threadIdx.x;
    if (i < N_NODES) {
        int rs = atomicAdd(cursor, deg[i]);
        row_start[i] = rs;
        cur[i] = rs;
    }
}

__global__ void bucket_kernel(const int* __restrict__ src, const int* __restrict__ dst,
                              int* __restrict__ cur, int* __restrict__ esrc) {
    int e = blockIdx.x * 256 + threadIdx.x;
    if (e < N_EDGES) {
        int pos = atomicAdd(&cur[dst[e]], 1);
        esrc[pos] = src[e];
    }
}

// h' = (x @ W) * dis[row] -> bf16 bits. MFMA 16x16x32 bf16, one wave per 16-row strip.
__global__ void gemm_kernel(const void* __restrict__ xv, const void* __restrict__ Wv,
                            const int* __restrict__ flag, const float* __restrict__ dis,
                            unsigned short* __restrict__ h) {
    __shared__ unsigned short Wt[D * 136];  // W transposed [col][k], stride 136 (16B-aligned)
    int tid = threadIdx.x;
    int m = *flag;
    for (int idx = tid; idx < D * D; idx += 256) {
        int k = idx >> 7, c = idx & 127;
        Wt[c * 136 + k] = m ? ((const unsigned short*)Wv)[idx]
                            : f2bf(((const float*)Wv)[idx]);
    }
    __syncthreads();

    int wave = tid >> 6, lane = tid & 63;
    int row0 = (blockIdx.x * 4 + wave) * 16;
    if (row0 >= N_NODES) return;
    int r = lane & 15, quad = lane >> 4;

    short8 a[4];  // a[t][j] = x[row0+r][t*32 + quad*8 + j]  (A: m=lane&15, k=quad*8+j)
    if (m) {
        const unsigned short* xr = (const unsigned short*)xv + (size_t)(row0 + r) * D + quad * 8;
        #pragma unroll
        for (int t = 0; t < 4; ++t) a[t] = *(const short8*)(xr + t * 32);
    } else {
        const float* xr = (const float*)xv + (size_t)(row0 + r) * D + quad * 8;
        #pragma unroll
        for (int t = 0; t < 4; ++t)
            for (int j = 0; j < 8; ++j) a[t][j] = (short)f2bf(xr[t * 32 + j]);
    }

    float sc[4];
    #pragma unroll
    for (int reg = 0; reg < 4; ++reg) sc[reg] = dis[row0 + quad * 4 + reg];

    #pragma unroll
    for (int ct = 0; ct < 8; ++ct) {
        int col0 = ct * 16;
        float4v c = {0.f, 0.f, 0.f, 0.f};
        #pragma unroll
        for (int t = 0; t < 4; ++t) {
            short8 bfr = *(const short8*)&Wt[(col0 + r) * 136 + t * 32 + quad * 8];
            c = __builtin_amdgcn_mfma_f32_16x16x32_bf16(a[t], bfr, c, 0, 0, 0);
        }
        #pragma unroll
        for (int reg = 0; reg < 4; ++reg) {
            int orow = row0 + quad * 4 + reg;  // C/D: col=lane&15, row=quad*4+reg (m89/m91)
            h[(size_t)orow * D + col0 + r] = f2bf(c[reg] * sc[reg]);
        }
    }
}

// One wave per node: acc = h'[n] + sum_{in-edges} h'[src]; out = relu(dis[n]*acc + b)
__global__ void aggregate_kernel(const int* __restrict__ esrc, const int* __restrict__ row_start,
                                 const int* __restrict__ deg, const float* __restrict__ dis,
                                 const float* __restrict__ bfv, const int* __restrict__ flag,
                                 const unsigned short* __restrict__ h, void* __restrict__ out) {
    int n = blockIdx.x * 4 + (threadIdx.x >> 6);
    if (n >= N_NODES) return;
    int lane = threadIdx.x & 63;
    size_t hbase = (size_t)n * D;

    unsigned int p0 = *(const unsigned int*)(h + hbase + lane * 2);
    float ax = bflo(p0), ay = bfhi(p0);

    int rs = row_start[n], dg = deg[n];
    for (int base = 0; base < dg; base += 64) {
        int rem = dg - base;
        int e_my = (lane < rem) ? esrc[rs + base + lane] : 0;
        int cnt = rem < 64 ? rem : 64;
        for (int j = 0; j < cnt; ++j) {
            int s = __shfl(e_my, j);
            unsigned int p = *(const unsigned int*)(h + (size_t)s * D + lane * 2);
            ax += bflo(p);
            ay += bfhi(p);
        }
    }

    float dn = dis[n];
    float vx = fmaxf(dn * ax + bfv[lane * 2], 0.f);
    float vy = fmaxf(dn * ay + bfv[lane * 2 + 1], 0.f);
    if (*flag) {
        unsigned int pk = ((unsigned int)f2bf(vy) << 16) | (unsigned int)f2bf(vx);
        *(unsigned int*)((unsigned short*)out + hbase + lane * 2) = pk;
    } else {
        float* of = (float*)out + hbase + lane * 2;
        of[0] = vx; of[1] = vy;
    }
}

extern "C" void kernel_launch(void* const* d_in, const int* in_sizes, int n_in,
                              void* d_out, int out_size, void* d_ws, size_t ws_size,
                              hipStream_t stream) {
    const void* x = nullptr; const int* ei = nullptr;
    const void* W = nullptr; const void* b = nullptr;
    for (int i = 0; i < n_in; ++i) {
        if      (in_sizes[i] == N_NODES * D) x  = d_in[i];
        else if (in_sizes[i] == 2 * N_EDGES) ei = (const int*)d_in[i];
        else if (in_sizes[i] == D * D)       W  = d_in[i];
        else if (in_sizes[i] == D)           b  = d_in[i];
    }
    if (!x || !ei || !W || !b) {
        x = d_in[0]; ei = (const int*)d_in[1]; W = d_in[2]; b = d_in[3];
    }
    const int* src = ei;            // edge_index[0]
    const int* dst = ei + N_EDGES;  // edge_index[1]

    // ws: flag(16) | cursor(16) | deg N | cur N | row_start N | dis N f32 | bfv 128 f32 | esrc E | h N*D
    char* ws = (char*)d_ws;
    int*   flag      = (int*)ws;
    int*   cursor    = (int*)(ws + 16);
    int*   deg       = (int*)(ws + 32);
    int*   cur       = deg + N_NODES;
    int*   row_start = cur + N_NODES;
    float* dis       = (float*)(row_start + N_NODES);
    float* bfv       = dis + N_NODES;
    int*   esrc      = (int*)(bfv + D);
    unsigned short* h = (unsigned short*)(esrc + N_EDGES);

    hipMemsetAsync(deg, 0, sizeof(int) * N_NODES, stream);
    hipMemsetAsync(cursor, 0, 16, stream);

    probe_kernel<<<1, 256, 0, stream>>>((const unsigned int*)x, flag);
    convert_b_kernel<<<1, 256, 0, stream>>>(b, flag, bfv);

    deg_count_kernel<<<(N_EDGES + 255) / 256, 256, 0, stream>>>(dst, deg);
    dis_kernel<<<(N_NODES + 255) / 256, 256, 0, stream>>>(deg, dis);
    rowstart_kernel<<<(N_NODES + 255) / 256, 256, 0, stream>>>(deg, cursor, row_start, cur);
    bucket_kernel<<<(N_EDGES + 255) / 256, 256, 0, stream>>>(src, dst, cur, esrc);

    gemm_kernel<<<(N_NODES + 63) / 64, 256, 0, stream>>>(x, W, flag, dis, h);

    aggregate_kernel<<<(N_NODES + 3) / 4, 256, 0, stream>>>(esrc, row_start, deg, dis, bfv, flag, h, d_out);
}